// Round 4
// baseline (364.689 us; speedup 1.0000x reference)
//
#include <hip/hip_runtime.h>
#include <math.h>

#define B_   256
#define IN_  512
#define C_   4
#define M_   6
#define K_   64
#define S1_  255
#define S2_  63

#define NBLK1 (C_ * S1_)                 // 1020
#define NBLK2 (C_ * S2_)                 // 252
#define NBLK3 (C_)                       // 4
#define NBLK_ALL (NBLK1 + NBLK2 + NBLK3) // 1276

#define LMIN_ (-6.906754778648554f)
#define LMAX_ ( 6.906754778648554f)
#define LR_   0.001f
#define WCLIP_ 5.0f

__device__ __forceinline__ float clampf(float v, float lo, float hi) {
    return fminf(fmaxf(v, lo), hi);
}

// One-time prep: xT[i][b], l0[b][i]; bias columns of out1RM/out2RM.
__global__ __launch_bounds__(256) void prep_kernel(const float* __restrict__ x,
                                                   const float* __restrict__ bias1,
                                                   const float* __restrict__ bias2,
                                                   float* __restrict__ xT,
                                                   float* __restrict__ l0,
                                                   float* __restrict__ out1RM,
                                                   float* __restrict__ out2RM) {
    __shared__ float tx_[32][33];
    const int i0 = (blockIdx.x & 15) * 32;   // IN/32 = 16 tiles
    const int b0 = (blockIdx.x >> 4) * 32;   // B/32  = 8 tiles
    const int tx = threadIdx.x & 31;
    const int ty = threadIdx.x >> 5;         // 0..7
#pragma unroll
    for (int r = 0; r < 4; ++r) {
        int bb = b0 + ty + 8 * r;
        int ii = i0 + tx;
        float xv = x[(size_t)bb * IN_ + ii];
        float xc = clampf(xv, 0.001f, 0.999f);
        float lv = (ii == 0) ? 0.0f : logf(xc / (1.0f - xc));
        l0[(size_t)bb * IN_ + ii] = lv;
        tx_[ty + 8 * r][tx] = xv;
    }
    __syncthreads();
#pragma unroll
    for (int r = 0; r < 4; ++r) {
        int ii = i0 + ty + 8 * r;
        int bb = b0 + tx;
        xT[(size_t)ii * B_ + bb] = tx_[tx][ty + 8 * r];
    }
    int gid = blockIdx.x * 256 + threadIdx.x;
    if (gid < C_ * B_) {
        int c = gid >> 8, b = gid & 255;
        out1RM[((size_t)c * B_ + b) * (S1_ + 1)] = bias1[c];
        out2RM[((size_t)c * B_ + b) * (S2_ + 1)] = bias2[c];
    }
}

// Routing for ALL layers: one block per (c,s) row-group; thread = batch b.
__global__ __launch_bounds__(256) void route_kernel(
    const float* __restrict__ xT,       // [IN][B]
    const float* __restrict__ cmaps1,   // [C][S1][M][IN]
    const float* __restrict__ cmaps2,
    const float* __restrict__ cmaps3,
    int* __restrict__ idx_buf)          // [NBLK_ALL][B]
{
    const int bid = blockIdx.x;
    const float* cmp;
    if (bid < NBLK1)              cmp = cmaps1 + (size_t)bid * M_ * IN_;
    else if (bid < NBLK1 + NBLK2) cmp = cmaps2 + (size_t)(bid - NBLK1) * M_ * IN_;
    else                          cmp = cmaps3 + (size_t)(bid - NBLK1 - NBLK2) * M_ * IN_;

    const int b = threadIdx.x;
    float acc[M_];
#pragma unroll
    for (int m = 0; m < M_; ++m) acc[m] = 0.0f;

    for (int k = 0; k < IN_; k += 8) {
        float xv[8];
#pragma unroll
        for (int j = 0; j < 8; ++j) xv[j] = xT[(size_t)(k + j) * B_ + b];  // coalesced, L2-hot
#pragma unroll
        for (int j = 0; j < 8; ++j)
#pragma unroll
            for (int m = 0; m < M_; ++m)
                acc[m] = fmaf(cmp[(size_t)m * IN_ + k + j], xv[j], acc[m]); // uniform -> s_load
    }
    int myidx = 0;
#pragma unroll
    for (int m = 0; m < M_; ++m) myidx |= (acc[m] > 0.0f) ? (1 << m) : 0;

    idx_buf[(size_t)bid * B_ + b] = myidx;
}

// Wave-per-bucket-row layer kernel. 4 waves/block; wave owns row k of tile.
// No LDS, no barriers. w row lives in registers: dot for bucket members,
// then in-register update with the winner's (last b's) diff and lg.
template<int DIN>
__global__ __launch_bounds__(256) void layer_kernel(
    const float* __restrict__ lg,      // rows [b][DIN]; c-offset via lg_sc
    long lg_sc,
    const int* __restrict__ target,
    const float* __restrict__ w,       // [tiles][K][DIN]
    float* __restrict__ nw,
    float* __restrict__ onext,         // [c][b][S+1]  or logits [b][C] if last
    const int* __restrict__ idx_buf,   // [tiles][B]
    int S, int is_last)
{
    const int tile = blockIdx.x >> 4;
    const int c    = tile / S;
    const int s    = tile - c * S;
    const int lane = threadIdx.x & 63;
    const int k    = ((blockIdx.x & 15) << 2) + (threadIdx.x >> 6);

    // bucket membership via ballot over the tile's idx row
    const int* idxp = idx_buf + (size_t)tile * B_;
    unsigned long long mask[4];
#pragma unroll
    for (int g = 0; g < 4; ++g) {
        int iv = idxp[g * 64 + lane];
        mask[g] = __ballot(iv == k);
    }

    // w row -> registers
    const float* wrow = w + ((size_t)tile * K_ + k) * DIN;
    float4 wq0, wq1; float ws0;
    if constexpr (DIN >= 256) {
        wq0 = *(const float4*)(wrow + lane * 4);
        if constexpr (DIN == 512) wq1 = *(const float4*)(wrow + 256 + lane * 4);
    } else {
        ws0 = wrow[lane];
    }

    const float* lgc = lg + (size_t)c * lg_sc;

    float dcur = 0.0f;
    bool  any  = false;
    float4 ls0, ls1; float lss0;

#pragma unroll
    for (int g = 0; g < 4; ++g) {
        unsigned long long m = mask[g];
        while (m) {
            int b = (g << 6) + __builtin_ctzll(m);
            m &= m - 1;

            float part;
            float4 lq0, lq1; float lqs;
            if constexpr (DIN == 512) {
                lq0 = *(const float4*)(lgc + (size_t)b * DIN + lane * 4);
                lq1 = *(const float4*)(lgc + (size_t)b * DIN + 256 + lane * 4);
                part = fmaf(wq0.x, lq0.x, fmaf(wq0.y, lq0.y,
                       fmaf(wq0.z, lq0.z, fmaf(wq0.w, lq0.w,
                       fmaf(wq1.x, lq1.x, fmaf(wq1.y, lq1.y,
                       fmaf(wq1.z, lq1.z, wq1.w * lq1.w)))))));
            } else if constexpr (DIN == 256) {
                lq0 = *(const float4*)(lgc + (size_t)b * DIN + lane * 4);
                part = fmaf(wq0.x, lq0.x, fmaf(wq0.y, lq0.y,
                       fmaf(wq0.z, lq0.z, wq0.w * lq0.w)));
            } else {
                lqs  = lgc[(size_t)b * DIN + lane];
                part = ws0 * lqs;
            }
#pragma unroll
            for (int off = 1; off < 64; off <<= 1)
                part += __shfl_xor(part, off);

            float outv = clampf(part, LMIN_, LMAX_);
            if (lane == 0) {
                if (is_last) onext[(size_t)b * C_ + c] = outv;
                else         onext[((size_t)c * B_ + b) * (size_t)(S + 1) + (s + 1)] = outv;
            }
            float tg = (target[b] == c) ? 1.0f : 0.0f;
            dcur = LR_ * (1.0f / (1.0f + expf(-outv)) - tg);
            if constexpr (DIN >= 256) {
                ls0 = lq0;
                if constexpr (DIN == 512) ls1 = lq1;
            } else {
                lss0 = lqs;
            }
            any = true;
        }
    }

    if (any) {
        if constexpr (DIN >= 256) {
            wq0.x = clampf(wq0.x - dcur * ls0.x, -WCLIP_, WCLIP_);
            wq0.y = clampf(wq0.y - dcur * ls0.y, -WCLIP_, WCLIP_);
            wq0.z = clampf(wq0.z - dcur * ls0.z, -WCLIP_, WCLIP_);
            wq0.w = clampf(wq0.w - dcur * ls0.w, -WCLIP_, WCLIP_);
            if constexpr (DIN == 512) {
                wq1.x = clampf(wq1.x - dcur * ls1.x, -WCLIP_, WCLIP_);
                wq1.y = clampf(wq1.y - dcur * ls1.y, -WCLIP_, WCLIP_);
                wq1.z = clampf(wq1.z - dcur * ls1.z, -WCLIP_, WCLIP_);
                wq1.w = clampf(wq1.w - dcur * ls1.w, -WCLIP_, WCLIP_);
            }
        } else {
            ws0 = clampf(ws0 - dcur * lss0, -WCLIP_, WCLIP_);
        }
    }

    float* nrow = nw + ((size_t)tile * K_ + k) * DIN;
    if constexpr (DIN >= 256) {
        *(float4*)(nrow + lane * 4) = wq0;
        if constexpr (DIN == 512) *(float4*)(nrow + 256 + lane * 4) = wq1;
    } else {
        nrow[lane] = ws0;
    }
}

extern "C" void kernel_launch(void* const* d_in, const int* in_sizes, int n_in,
                              void* d_out, int out_size, void* d_ws, size_t ws_size,
                              hipStream_t stream) {
    const float* x      = (const float*)d_in[0];
    const int*   target = (const int*)  d_in[1];
    const float* cmaps1 = (const float*)d_in[2];
    const float* w1     = (const float*)d_in[3];
    const float* bias1  = (const float*)d_in[4];
    const float* cmaps2 = (const float*)d_in[5];
    const float* w2     = (const float*)d_in[6];
    const float* bias2  = (const float*)d_in[7];
    const float* cmaps3 = (const float*)d_in[8];
    const float* w3     = (const float*)d_in[9];
    float* out = (float*)d_out;

    float* xT     = (float*)d_ws;                           // IN*B
    float* l0     = xT     + (size_t)IN_ * B_;              // B*IN
    float* out1RM = l0     + (size_t)B_ * IN_;              // C*B*(S1+1)
    float* out2RM = out1RM + (size_t)C_ * B_ * (S1_ + 1);   // C*B*(S2+1)
    int*   idx_buf = (int*)(out2RM + (size_t)C_ * B_ * (S2_ + 1));  // NBLK_ALL*B

    float* logits = out;
    float* nw1 = out + (size_t)B_ * C_;
    float* nw2 = nw1 + (size_t)C_ * S1_ * K_ * IN_;
    float* nw3 = nw2 + (size_t)C_ * S2_ * K_ * (S1_ + 1);

    prep_kernel<<<dim3(128), dim3(256), 0, stream>>>(x, bias1, bias2, xT, l0, out1RM, out2RM);

    route_kernel<<<dim3(NBLK_ALL), dim3(256), 0, stream>>>(
        xT, cmaps1, cmaps2, cmaps3, idx_buf);

    // layer 1: lg = l0 (c-stride 0)
    layer_kernel<512><<<dim3(NBLK1 * 16), dim3(256), 0, stream>>>(
        l0, 0L, target, w1, nw1, out1RM, idx_buf, S1_, 0);

    // layer 2: lg = out1RM [c][b][S1+1]
    layer_kernel<256><<<dim3(NBLK2 * 16), dim3(256), 0, stream>>>(
        out1RM, (long)B_ * (S1_ + 1), target, w2, nw2, out2RM,
        idx_buf + (size_t)NBLK1 * B_, S2_, 0);

    // layer 3: lg = out2RM [c][b][S2+1]; writes logits
    layer_kernel<64><<<dim3(NBLK3 * 16), dim3(256), 0, stream>>>(
        out2RM, (long)B_ * (S2_ + 1), target, w3, nw3, logits,
        idx_buf + (size_t)(NBLK1 + NBLK2) * B_, 1, 1);
}

// Round 5
// 193.156 us; speedup vs baseline: 1.8881x; 1.8881x over previous
//
#include <hip/hip_runtime.h>
#include <math.h>

#define B_   256
#define IN_  512
#define C_   4
#define M_   6
#define K_   64
#define S1_  255
#define S2_  63

#define NBLK1 (C_ * S1_)                 // 1020
#define NBLK2 (C_ * S2_)                 // 252
#define NBLK3 (C_)                       // 4
#define NBLK_ALL (NBLK1 + NBLK2 + NBLK3) // 1276

#define LMIN_ (-6.906754778648554f)
#define LMAX_ ( 6.906754778648554f)
#define LR_   0.001f
#define WCLIP_ 5.0f

__device__ __forceinline__ float clampf(float v, float lo, float hi) {
    return fminf(fmaxf(v, lo), hi);
}

// One-time prep: xT[i][b], l0[b][i], l0T[i][b]; bias columns of out1/out2 (both layouts).
__global__ __launch_bounds__(256) void prep_kernel(const float* __restrict__ x,
                                                   const float* __restrict__ bias1,
                                                   const float* __restrict__ bias2,
                                                   float* __restrict__ xT,
                                                   float* __restrict__ l0,
                                                   float* __restrict__ l0T,
                                                   float* __restrict__ out1T,
                                                   float* __restrict__ out1RM,
                                                   float* __restrict__ out2T,
                                                   float* __restrict__ out2RM) {
    __shared__ float tx_[32][33];
    __shared__ float tl_[32][33];
    const int i0 = (blockIdx.x & 15) * 32;   // IN/32 = 16 tiles
    const int b0 = (blockIdx.x >> 4) * 32;   // B/32  = 8 tiles
    const int tx = threadIdx.x & 31;
    const int ty = threadIdx.x >> 5;         // 0..7
#pragma unroll
    for (int r = 0; r < 4; ++r) {
        int bb = b0 + ty + 8 * r;
        int ii = i0 + tx;
        float xv = x[(size_t)bb * IN_ + ii];
        float xc = clampf(xv, 0.001f, 0.999f);
        float lv = (ii == 0) ? 0.0f : logf(xc / (1.0f - xc));
        l0[(size_t)bb * IN_ + ii] = lv;
        tx_[ty + 8 * r][tx] = xv;
        tl_[ty + 8 * r][tx] = lv;
    }
    __syncthreads();
#pragma unroll
    for (int r = 0; r < 4; ++r) {
        int ii = i0 + ty + 8 * r;
        int bb = b0 + tx;
        xT[(size_t)ii * B_ + bb]  = tx_[tx][ty + 8 * r];
        l0T[(size_t)ii * B_ + bb] = tl_[tx][ty + 8 * r];
    }
    int gid = blockIdx.x * 256 + threadIdx.x;
    if (gid < C_ * B_) {
        int c = gid >> 8, b = gid & 255;
        float b1 = bias1[c], b2 = bias2[c];
        out1T[((size_t)c * (S1_ + 1)) * B_ + b] = b1;
        out1RM[((size_t)c * B_ + b) * (S1_ + 1)] = b1;
        out2T[((size_t)c * (S2_ + 1)) * B_ + b] = b2;
        out2RM[((size_t)c * B_ + b) * (S2_ + 1)] = b2;
    }
}

// Routing for ALL layers: one block per (c,s); thread = batch b.
__global__ __launch_bounds__(256) void route_kernel(
    const float* __restrict__ xT,       // [IN][B]
    const float* __restrict__ cmaps1,   // [C][S1][M][IN]
    const float* __restrict__ cmaps2,
    const float* __restrict__ cmaps3,
    int* __restrict__ idx_buf)          // [NBLK_ALL][B]
{
    const int bid = blockIdx.x;
    const float* cmp;
    if (bid < NBLK1)              cmp = cmaps1 + (size_t)bid * M_ * IN_;
    else if (bid < NBLK1 + NBLK2) cmp = cmaps2 + (size_t)(bid - NBLK1) * M_ * IN_;
    else                          cmp = cmaps3 + (size_t)(bid - NBLK1 - NBLK2) * M_ * IN_;

    const int b = threadIdx.x;
    float acc[M_];
#pragma unroll
    for (int m = 0; m < M_; ++m) acc[m] = 0.0f;

    for (int k = 0; k < IN_; k += 8) {
        float xv[8];
#pragma unroll
        for (int j = 0; j < 8; ++j) xv[j] = xT[(size_t)(k + j) * B_ + b];  // coalesced, L2-hot
#pragma unroll
        for (int j = 0; j < 8; ++j)
#pragma unroll
            for (int m = 0; m < M_; ++m)
                acc[m] = fmaf(cmp[(size_t)m * IN_ + k + j], xv[j], acc[m]); // uniform -> s_load
    }
    int myidx = 0;
#pragma unroll
    for (int m = 0; m < M_; ++m) myidx |= (acc[m] > 0.0f) ? (1 << m) : 0;

    idx_buf[(size_t)bid * B_ + b] = myidx;
}

// Fused dot+update, block = (tile, row-quarter). 256 threads; thread = batch b.
// Block owns 16 bucket rows; all members of those rows are its active threads.
template<int DIN>
__global__ __launch_bounds__(256) void layer_kernel(
    const float* __restrict__ lgT,     // lgT[c*lgT_sc + k*B + b]
    const float* __restrict__ lgRM,    // lgRM[c*lg_sc + b*DIN + k]
    long lgT_sc, long lg_sc,
    const int* __restrict__ target,
    const float* __restrict__ w,       // [tiles][K][DIN]
    float* __restrict__ nw,
    float* __restrict__ onextT,        // [c][S+1][b]  (null if last)
    float* __restrict__ onextRM,       // [c][b][S+1], or logits[b][C] if last
    const int* __restrict__ idx_buf,   // [tiles][B]
    int S, int is_last)
{
    constexpr int RPB = 16;            // rows per block (K/4)
    constexpr int WCHv = 64;           // k-chunk width
    constexpr int NT  = DIN / WCHv;
    constexpr int QPR = DIN / 4;       // float4 per row

    __shared__ float wl[2][RPB][WCHv + 1];
    __shared__ float diff_s[B_];
    __shared__ float dw_s[RPB];
    __shared__ int   win_s[RPB];

    const int tile = blockIdx.x >> 2;
    const int q    = blockIdx.x & 3;
    const int c    = tile / S;
    const int s    = tile - c * S;
    const int tid  = threadIdx.x;
    const int b    = tid;
    const int r0   = q * RPB;

    if (tid < RPB) win_s[tid] = -1;

    const int myidx  = idx_buf[(size_t)tile * B_ + b];
    const int myrow  = myidx - r0;
    const bool active = (myrow >= 0) && (myrow < RPB);

    const float* wp   = w + ((size_t)tile * K_ + r0) * DIN;   // block's 16 rows
    const float* lgTc = lgT + (size_t)c * lgT_sc;

    const int srow = tid >> 4;               // staging: 16 threads per row
    const int skq  = (tid & 15) << 2;

    // reg-staged double-buffered dot: 1 barrier per chunk
    float4 pre = *(const float4*)(wp + (size_t)srow * DIN + skq);
    float dot = 0.0f;
    for (int t = 0; t < NT; ++t) {
        const int cur = t & 1;
        wl[cur][srow][skq + 0] = pre.x;
        wl[cur][srow][skq + 1] = pre.y;
        wl[cur][srow][skq + 2] = pre.z;
        wl[cur][srow][skq + 3] = pre.w;
        if (t + 1 < NT)
            pre = *(const float4*)(wp + (size_t)srow * DIN + (t + 1) * WCHv + skq);
        __syncthreads();
        if (active) {
#pragma unroll
            for (int kk = 0; kk < WCHv; ++kk)
                dot = fmaf(wl[cur][myrow][kk], lgTc[(size_t)(t * WCHv + kk) * B_ + b], dot);
        }
    }

    if (active) {
        float outv = clampf(dot, LMIN_, LMAX_);
        if (is_last) {
            onextRM[(size_t)b * C_ + c] = outv;
        } else {
            onextT[((size_t)c * (S + 1) + (s + 1)) * B_ + b] = outv;
            onextRM[((size_t)c * B_ + b) * (size_t)(S + 1) + (s + 1)] = outv;
        }
        float tg = (target[b] == c) ? 1.0f : 0.0f;
        diff_s[b] = 1.0f / (1.0f + expf(-outv)) - tg;
        atomicMax(&win_s[myrow], b);         // last-b-wins == max b
    }
    __syncthreads();
    if (tid < RPB) {
        int bw = win_s[tid];
        dw_s[tid] = (bw >= 0) ? LR_ * diff_s[bw] : 0.0f;
    }
    __syncthreads();

    // update stream: block's 16 rows, read w once more (L2/L3-hot), write nw
    const float* lgc = lgRM + (size_t)c * lg_sc;
    float* nwp = nw + ((size_t)tile * K_ + r0) * DIN;
#pragma unroll
    for (int j = 0; j < (RPB * QPR) / 256; ++j) {
        int Q   = tid + 256 * j;
        int row = Q / QPR;
        int col = (Q - row * QPR) << 2;
        float4 wv = *(const float4*)(wp + (size_t)row * DIN + col);
        int bw = win_s[row];
        if (bw >= 0) {
            float d = dw_s[row];
            const float4 lv = *(const float4*)(lgc + (size_t)bw * DIN + col);
            wv.x = clampf(wv.x - d * lv.x, -WCLIP_, WCLIP_);
            wv.y = clampf(wv.y - d * lv.y, -WCLIP_, WCLIP_);
            wv.z = clampf(wv.z - d * lv.z, -WCLIP_, WCLIP_);
            wv.w = clampf(wv.w - d * lv.w, -WCLIP_, WCLIP_);
        }
        *(float4*)(nwp + (size_t)row * DIN + col) = wv;
    }
}

extern "C" void kernel_launch(void* const* d_in, const int* in_sizes, int n_in,
                              void* d_out, int out_size, void* d_ws, size_t ws_size,
                              hipStream_t stream) {
    const float* x      = (const float*)d_in[0];
    const int*   target = (const int*)  d_in[1];
    const float* cmaps1 = (const float*)d_in[2];
    const float* w1     = (const float*)d_in[3];
    const float* bias1  = (const float*)d_in[4];
    const float* cmaps2 = (const float*)d_in[5];
    const float* w2     = (const float*)d_in[6];
    const float* bias2  = (const float*)d_in[7];
    const float* cmaps3 = (const float*)d_in[8];
    const float* w3     = (const float*)d_in[9];
    float* out = (float*)d_out;

    float* xT     = (float*)d_ws;                           // IN*B
    float* l0     = xT     + (size_t)IN_ * B_;              // B*IN
    float* l0T    = l0     + (size_t)B_ * IN_;              // IN*B
    float* out1T  = l0T    + (size_t)IN_ * B_;              // C*(S1+1)*B
    float* out1RM = out1T  + (size_t)C_ * (S1_ + 1) * B_;   // C*B*(S1+1)
    float* out2T  = out1RM + (size_t)C_ * B_ * (S1_ + 1);   // C*(S2+1)*B
    float* out2RM = out2T  + (size_t)C_ * (S2_ + 1) * B_;   // C*B*(S2+1)
    int*   idx_buf = (int*)(out2RM + (size_t)C_ * B_ * (S2_ + 1));  // NBLK_ALL*B

    float* logits = out;
    float* nw1 = out + (size_t)B_ * C_;
    float* nw2 = nw1 + (size_t)C_ * S1_ * K_ * IN_;
    float* nw3 = nw2 + (size_t)C_ * S2_ * K_ * (S1_ + 1);

    prep_kernel<<<dim3(128), dim3(256), 0, stream>>>(
        x, bias1, bias2, xT, l0, l0T, out1T, out1RM, out2T, out2RM);

    route_kernel<<<dim3(NBLK_ALL), dim3(256), 0, stream>>>(
        xT, cmaps1, cmaps2, cmaps3, idx_buf);

    // layer 1: lg = l0 (c-stride 0)
    layer_kernel<512><<<dim3(NBLK1 * 4), dim3(256), 0, stream>>>(
        l0T, l0, 0L, 0L, target, w1, nw1, out1T, out1RM, idx_buf, S1_, 0);

    // layer 2: lg = out1 [c][b][S1+1]
    layer_kernel<256><<<dim3(NBLK2 * 4), dim3(256), 0, stream>>>(
        out1T, out1RM, (long)(S1_ + 1) * B_, (long)B_ * (S1_ + 1), target, w2, nw2,
        out2T, out2RM, idx_buf + (size_t)NBLK1 * B_, S2_, 0);

    // layer 3: lg = out2 [c][b][S2+1]; writes logits
    layer_kernel<64><<<dim3(NBLK3 * 4), dim3(256), 0, stream>>>(
        out2T, out2RM, (long)(S2_ + 1) * B_, (long)B_ * (S2_ + 1), target, w3, nw3,
        nullptr, logits, idx_buf + (size_t)(NBLK1 + NBLK2) * B_, 1, 1);
}